// Round 12
// baseline (107.440 us; speedup 1.0000x reference)
//
#include <hip/hip_runtime.h>
#include <hip/hip_bf16.h>

#define TLEN 4096
#define NINP 256
#define DD   64

// 1/sqrt(64) * log2(e): folded into WqT so softmax = exp2(s)
#define QSCALE 0.18033688011112042f

typedef __attribute__((ext_vector_type(8))) short bf16x8;
typedef __attribute__((ext_vector_type(4))) short bf16x4;
typedef __attribute__((ext_vector_type(4))) float f32x4;

union U8 { bf16x8 v; uint u[4]; };
union U4 { bf16x4 v; uint u[2]; };

// fp32 -> bf16 RNE (manual; v_cvt_pk_bf16_f32 is NOT RNE -> used only where
// bias is cancelled: P-weights, numerator AND denominator)
__device__ inline ushort bfu(float x) {
    union { float f; uint u; } a; a.f = x;
    uint r = a.u + 0x7fffu + ((a.u >> 16) & 1u);
    return (ushort)(r >> 16);
}
__device__ inline uint pk2(float lo, float hi) {
    return (uint)bfu(lo) | ((uint)bfu(hi) << 16);
}
// hardware packed cvt (non-RNE): P-only (scale-invariance cancels bias)
__device__ inline uint cvtpk(float lo, float hi) {
    uint r;
    asm("v_cvt_pk_bf16_f32 %0, %1, %2" : "=v"(r) : "v"(lo), "v"(hi));
    return r;
}

__device__ inline bf16x8 ld16(const ushort* p) {  // 16B-aligned global/LDS
    return *(const bf16x8*)p;
}

// ---------------------------------------------------------------------------
// prep: WTf[m] in FRAG-NATIVE layout: unit u=(s*4+nt), slot = u*64+lane,
// 16B at slot*8 = W^T[d=nt*16+(lane&15)][k=s*32+(lane>>4)*8 .. +7], Wq scaled.
// ---------------------------------------------------------------------------
__global__ __launch_bounds__(256) void prep_wt(
    const float* __restrict__ Wq, const float* __restrict__ Wk,
    const float* __restrict__ Wv, ushort* __restrict__ WTf)
{
    __shared__ ushort lt[256 * 66];   // [k][d] padded
    const int t = threadIdx.x;
    const int m = blockIdx.x;
    const float* W = (m == 0) ? Wq : ((m == 1) ? Wk : Wv);
    const float scale = (m == 0) ? QSCALE : 1.0f;

    #pragma unroll
    for (int j = 0; j < 16; ++j) {
        int i4 = t + 256 * j;                 // float4 index
        float4 v = *(const float4*)&W[i4 * 4];
        int k = i4 >> 4, d = (i4 * 4) & 63;
        *(uint*)&lt[k * 66 + d]     = pk2(v.x * scale, v.y * scale);
        *(uint*)&lt[k * 66 + d + 2] = pk2(v.z * scale, v.w * scale);
    }
    __syncthreads();
    #pragma unroll
    for (int j = 0; j < 8; ++j) {
        int slot = t + 256 * j;               // 2048 slots x 8 ushort
        int u = slot >> 6, ln = slot & 63;
        int s = u >> 2, nt = u & 3;
        int d = nt * 16 + (ln & 15);
        int k0 = s * 32 + (ln >> 4) * 8;
        uint a0 = (uint)lt[(k0 + 0) * 66 + d] | ((uint)lt[(k0 + 1) * 66 + d] << 16);
        uint a1 = (uint)lt[(k0 + 2) * 66 + d] | ((uint)lt[(k0 + 3) * 66 + d] << 16);
        uint a2 = (uint)lt[(k0 + 4) * 66 + d] | ((uint)lt[(k0 + 5) * 66 + d] << 16);
        uint a3 = (uint)lt[(k0 + 6) * 66 + d] | ((uint)lt[(k0 + 7) * 66 + d] << 16);
        ushort* gd = WTf + m * 16384 + slot * 8;
        ((uint2*)gd)[0] = uint2{a0, a1};
        ((uint2*)gd)[1] = uint2{a2, a3};
    }
}

// ---------------------------------------------------------------------------
// QKV: m-split grid (3 x rowblocks), 256 threads, 64 rows/block. B-fragments
// load directly from frag-native WTf (L1/L2-hit, coalesced ld16). mb=0: Q
// row-major. mb=1/2: K/V packed frag-native (R8).
// ---------------------------------------------------------------------------
__global__ __launch_bounds__(256) void qkv_kernel(
    const float* __restrict__ y, const ushort* __restrict__ WTf,
    ushort* __restrict__ Qh, ushort* __restrict__ Kp, ushort* __restrict__ Vp,
    const int rbn)
{
    __shared__ ushort tb[64 * 68];    //  8,704 B

    const int t = threadIdx.x;
    const int w = t >> 6, lane = t & 63;
    const int quad = lane >> 4, l15 = lane & 15;
    const int mb = blockIdx.x / rbn;       // 0=Q 1=K 2=V
    const int rb = blockIdx.x % rbn;       // rowblock == (batch*64 + chunk64)
    const int rowbase = rb * 64;
    const int myrow = rowbase + w * 16 + l15;

    // ---- A-fragments ----
    bf16x8 afrag[8];
    const float* yrow = y + (size_t)myrow * NINP;
    #pragma unroll
    for (int s = 0; s < 8; ++s) {
        float4 lo = *(const float4*)&yrow[s * 32 + quad * 8];
        float4 hi = *(const float4*)&yrow[s * 32 + quad * 8 + 4];
        U8 u;
        u.u[0] = pk2(lo.x, lo.y);
        u.u[1] = pk2(lo.z, lo.w);
        u.u[2] = pk2(hi.x, hi.y);
        u.u[3] = pk2(hi.z, hi.w);
        afrag[s] = u.v;
    }

    f32x4 acc[4];
    #pragma unroll
    for (int nt = 0; nt < 4; ++nt) acc[nt] = f32x4{0.f, 0.f, 0.f, 0.f};

    const ushort* Wm = WTf + mb * 16384 + lane * 8;
    #pragma unroll
    for (int s = 0; s < 8; ++s)
        #pragma unroll
        for (int nt = 0; nt < 4; ++nt) {
            bf16x8 bfrag = ld16(Wm + (s * 4 + nt) * 512);
            acc[nt] = __builtin_amdgcn_mfma_f32_16x16x32_bf16(
                afrag[s], bfrag, acc[nt], 0, 0, 0);
        }

    if (mb == 0) {
        // ---- Q row-major via LDS repack ----
        #pragma unroll
        for (int nt = 0; nt < 4; ++nt)
            #pragma unroll
            for (int r = 0; r < 4; ++r)
                tb[(w * 16 + quad * 4 + r) * 68 + nt * 16 + l15] = bfu(acc[nt][r]);
        __syncthreads();
        int row = t >> 2, seg = t & 3;
        ushort* gd = Qh + (size_t)(rowbase + row) * DD + seg * 16;
        const ushort* sp = &tb[row * 68 + seg * 16];
        #pragma unroll
        for (int j = 0; j < 4; ++j) ((uint2*)gd)[j] = ((const uint2*)sp)[j];
    } else if (mb == 1) {
        // ---- K packed: unit idx=(kt*2+s)*64+lane holds 16B of
        // K[row=kt*16+l15][d=s*32+quad*8..+7] ----
        #pragma unroll
        for (int nt = 0; nt < 4; ++nt)
            #pragma unroll
            for (int r = 0; r < 4; ++r)
                tb[(w * 16 + quad * 4 + r) * 68 + nt * 16 + l15] = bfu(acc[nt][r]);
        __syncthreads();
        #pragma unroll
        for (int j = 0; j < 2; ++j) {
            int idx = t + 256 * j;                 // 16B-unit 0..511
            int instr = idx >> 6, ln = idx & 63;
            int kt = instr >> 1, s = instr & 1;
            int q2 = ln >> 4, l15b = ln & 15;
            int row = kt * 16 + l15b, dcol = s * 32 + q2 * 8;
            const ushort* sp = &tb[row * 68 + dcol];
            ushort* gd = Kp + (size_t)rb * 4096 + idx * 8;
            ((uint2*)gd)[0] = ((const uint2*)sp)[0];
            ((uint2*)gd)[1] = ((const uint2*)sp)[1];
        }
    } else {
        // ---- V packed: unit idx=(nt*2+m)*64+lane holds two 8B halves
        // V^T[d=nt*16+l15][k=32m+16e+quad*4..+3], e=0,1 ----
        #pragma unroll
        for (int nt = 0; nt < 4; ++nt) {
            int d = nt * 16 + l15;
            #pragma unroll
            for (int r = 0; r < 4; r += 2) {
                int tt = w * 16 + quad * 4 + r;
                *(uint*)&tb[d * 68 + tt] = pk2(acc[nt][r], acc[nt][r + 1]);
            }
        }
        __syncthreads();
        #pragma unroll
        for (int j = 0; j < 2; ++j) {
            int idx = t + 256 * j;                 // 16B-unit 0..511
            int instr = idx >> 6, ln = idx & 63;
            int nt = instr >> 1, m = instr & 1;
            int q2 = ln >> 4, l15b = ln & 15;
            int d = nt * 16 + l15b;
            int k0 = 32 * m + q2 * 4;
            ushort* gd = Vp + (size_t)rb * 4096 + idx * 8;
            ((uint2*)gd)[0] = *(const uint2*)&tb[d * 68 + k0];
            ((uint2*)gd)[1] = *(const uint2*)&tb[d * 68 + k0 + 16];
        }
    }
}

// ===========================================================================
// Attention helpers: 32-key chunks, packed layout.
// ===========================================================================
__device__ inline void load_k32(bf16x8 (&kf)[2][2], const ushort* __restrict__ Kw,
                                int ci)
{
    const ushort* base = Kw + (size_t)ci * 2048;
    #pragma unroll
    for (int kt = 0; kt < 2; ++kt)
        #pragma unroll
        for (int s = 0; s < 2; ++s)
            kf[kt][s] = ld16(base + (kt * 2 + s) * 512);
}

__device__ inline void load_v32(U4 (&vt)[4][2], const ushort* __restrict__ Vw,
                                int ci)
{
    const ushort* base = Vw + (size_t)(ci >> 1) * 4096 + (ci & 1) * 512;
    #pragma unroll
    for (int nt = 0; nt < 4; ++nt) {
        U8 uu; uu.v = ld16(base + nt * 1024);
        vt[nt][0].u[0] = uu.u[0]; vt[nt][0].u[1] = uu.u[1];
        vt[nt][1].u[0] = uu.u[2]; vt[nt][1].u[1] = uu.u[3];
    }
}

// ---------------------------------------------------------------------------
// Attention R12: 64-QUERY waves -> per-CU VMEM HALVED (R8/R11 evidence: attn
// is VMEM-transaction-throughput bound; occupancy & prefetch depth are null).
// Each wave: 64 q x 32 k per chunk (qf[4][2], st[4][2], oT[4][4]; ~206 VGPR
// incl acc, fits 2 waves/SIMD cap 256 -- occupancy insensitivity proven).
// 256 blocks x 512 threads (8 waves, 1 block/CU): block (u,h) owns key-HALF
// h (segs h*8..h*8+7, snake-mirrored) of the 64-q tile pair (u, 63-u) ->
// ~66 chunk-loads/CU (was 129), uniform. Keys split across 2 blocks =>
// combine scope > block (R4 lesson) => blocks write fp32 PARTIALS (num+den,
// disjoint -> no race); norm_kernel sums the two halves and normalizes.
// XCD-batch clustering: batch=(id&7)>>1; both h-blocks of a unit land on the
// same XCD pair (x = 2b, 2b+1) -> K+V L2-resident.
// ---------------------------------------------------------------------------
__global__ __launch_bounds__(512, 2) void attn_kernel(
    const ushort* __restrict__ Qh, const ushort* __restrict__ Kp,
    const ushort* __restrict__ Vp, float* __restrict__ part_n,
    float* __restrict__ part_l)
{
    __shared__ float Ob[8][32 * 68];    // per-wave partial O (one q-half) padded
    __shared__ float lb[8][32];         // per-wave partial l

    const int t = threadIdx.x;
    const int w = t >> 6, lane = t & 63;
    const int quad = lane >> 4, l15 = lane & 15;

    const int x = blockIdx.x & 7;
    const int b = x >> 1;                 // batch
    const int h = x & 1;                  // key-half of the pair-unit
    const int u = (int)blockIdx.x >> 3;   // 0..31 pair index

    const ushort* Qb = Qh + (size_t)b * TLEN * DD;
    const ushort* Kw = Kp + (size_t)b * 64 * 4096 + lane * 8;
    const ushort* Vw = Vp + (size_t)b * 64 * 4096 + lane * 8;

    for (int half = 0; half < 2; ++half) {
        const int tile = half ? (63 - u) : u;         // 64-q tile 0..63
        const int seg  = half ? (15 - (h * 8 + w)) : (h * 8 + w);
        const int qb   = tile * 64;
        const int nc   = 2 * tile + 2;                // 32-key chunks
        const int cps  = (nc + 15) >> 4;
        const int clo  = seg * cps;
        const int chi  = (nc < clo + cps) ? nc : (clo + cps);

        f32x4 oT[4][4];        // O^T: d=nt*16+quad*4+r, q=qb+qt*16+l15
        #pragma unroll
        for (int qt = 0; qt < 4; ++qt)
            #pragma unroll
            for (int nt = 0; nt < 4; ++nt)
                oT[qt][nt] = f32x4{0.f, 0.f, 0.f, 0.f};
        float l_acc[4] = {0.f, 0.f, 0.f, 0.f};

        if (clo < chi) {
            // Q B-frags: 4 q-16 groups (64 queries)
            bf16x8 qf[4][2];
            #pragma unroll
            for (int qt = 0; qt < 4; ++qt)
                #pragma unroll
                for (int s = 0; s < 2; ++s)
                    qf[qt][s] = ld16(Qb + (size_t)(qb + qt * 16 + l15) * DD + s * 32 + quad * 8);

            bf16x8 kf[2][2];
            load_k32(kf, Kw, clo);

            for (int ci = clo; ci < chi; ++ci) {
                const int c0 = ci * 32;

                U4 vt[4][2];
                load_v32(vt, Vw, ci);

                // S^T = K·Q^T for 4 q-groups
                f32x4 st[4][2];
                #pragma unroll
                for (int qt = 0; qt < 4; ++qt)
                    #pragma unroll
                    for (int kt = 0; kt < 2; ++kt)
                        st[qt][kt] = f32x4{0.f, 0.f, 0.f, 0.f};
                __builtin_amdgcn_s_setprio(1);
                #pragma unroll
                for (int s = 0; s < 2; ++s)
                    #pragma unroll
                    for (int qt = 0; qt < 4; ++qt)
                        #pragma unroll
                        for (int kt = 0; kt < 2; ++kt)
                            st[qt][kt] = __builtin_amdgcn_mfma_f32_16x16x32_bf16(
                                kf[kt][s], qf[qt][s], st[qt][kt], 0, 0, 0);
                __builtin_amdgcn_s_setprio(0);

                if (ci + 1 < chi) load_k32(kf, Kw, ci + 1);

                // softmax weights -> bf16 P^T frags (cvt_pk; bias cancels)
                U4 pa[4][2];
                if (c0 + 31 <= qb) {            // unmasked for all 64 queries
                    #pragma unroll
                    for (int qt = 0; qt < 4; ++qt)
                        #pragma unroll
                        for (int kt = 0; kt < 2; ++kt) {
                            float p0 = exp2f(st[qt][kt][0]);
                            float p1 = exp2f(st[qt][kt][1]);
                            float p2 = exp2f(st[qt][kt][2]);
                            float p3 = exp2f(st[qt][kt][3]);
                            l_acc[qt] += (p0 + p1) + (p2 + p3);
                            pa[qt][kt].u[0] = cvtpk(p0, p1);
                            pa[qt][kt].u[1] = cvtpk(p2, p3);
                        }
                } else {                        // diagonal chunk: causal mask
                    #pragma unroll
                    for (int qt = 0; qt < 4; ++qt) {
                        const int q = qb + qt * 16 + l15;
                        #pragma unroll
                        for (int kt = 0; kt < 2; ++kt) {
                            const int kb0 = c0 + kt * 16 + quad * 4;
                            float p[4];
                            #pragma unroll
                            for (int r = 0; r < 4; ++r) {
                                float e = exp2f(st[qt][kt][r]);
                                p[r] = (kb0 + r <= q) ? e : 0.f;
                                l_acc[qt] += p[r];
                            }
                            pa[qt][kt].u[0] = cvtpk(p[0], p[1]);
                            pa[qt][kt].u[1] = cvtpk(p[2], p[3]);
                        }
                    }
                }

                // O^T += V^T·P^T
                __builtin_amdgcn_s_setprio(1);
                #pragma unroll
                for (int qt = 0; qt < 4; ++qt)
                    #pragma unroll
                    for (int nt = 0; nt < 4; ++nt)
                        #pragma unroll
                        for (int kt = 0; kt < 2; ++kt)
                            oT[qt][nt] = __builtin_amdgcn_mfma_f32_16x16x16bf16_1k(
                                vt[nt][kt].v, pa[qt][kt].v, oT[qt][nt], 0, 0, 0);
                __builtin_amdgcn_s_setprio(0);
            }

            // reduce l across quads (keys live in quads)
            #pragma unroll
            for (int qt = 0; qt < 4; ++qt) {
                l_acc[qt] += __shfl_xor(l_acc[qt], 16, 64);
                l_acc[qt] += __shfl_xor(l_acc[qt], 32, 64);
            }
        }

        // publish + write partials in two 32-q passes (LDS holds 32 rows)
        float* pn = part_n + ((size_t)((b * 64 + tile) * 2 + h)) * 4096;
        float* pl = part_l + ((size_t)((b * 64 + tile) * 2 + h)) * 64;
        #pragma unroll
        for (int pass = 0; pass < 2; ++pass) {
            #pragma unroll
            for (int ql = 0; ql < 2; ++ql) {
                int qt = pass * 2 + ql;
                #pragma unroll
                for (int nt = 0; nt < 4; ++nt)
                    #pragma unroll
                    for (int r = 0; r < 4; ++r)
                        Ob[w][(ql * 16 + l15) * 68 + nt * 16 + quad * 4 + r] = oT[qt][nt][r];
                if (quad == 0) lb[w][ql * 16 + l15] = l_acc[qt];
            }
            __syncthreads();
            #pragma unroll
            for (int e = 0; e < 4; ++e) {
                int idx = t + 512 * e;
                int q = idx >> 6, d = idx & 63;
                float s = 0.f, ls = 0.f;
                #pragma unroll
                for (int ww = 0; ww < 8; ++ww) {
                    s += Ob[ww][q * 68 + d];
                    ls += lb[ww][q];
                }
                pn[(pass * 32 + q) * 64 + d] = s;
                if (d == 0) pl[pass * 32 + q] = ls;
            }
            __syncthreads();
        }
    }
}

// ---------------------------------------------------------------------------
// normalize: out = (n0+n1) / (l0+l1) per query row. 256 blocks (b*64+tile)
// x 256 threads x 16 elems, fully coalesced.
// ---------------------------------------------------------------------------
__global__ __launch_bounds__(256) void norm_kernel(
    const float* __restrict__ part_n, const float* __restrict__ part_l,
    float* __restrict__ out)
{
    const int bt = blockIdx.x;             // 0..255 = b*64 + tile
    const size_t n0 = (size_t)bt * 2 * 4096;
    const size_t l0 = (size_t)bt * 2 * 64;
    float* ob = out + (size_t)bt * 4096;   // (b*4096 + tile*64) * 64 = bt*4096

    #pragma unroll
    for (int j = 0; j < 16; ++j) {
        int idx = threadIdx.x + 256 * j;   // 0..4095
        int q = idx >> 6;
        float n = part_n[n0 + idx] + part_n[n0 + 4096 + idx];
        float l = part_l[l0 + q] + part_l[l0 + 64 + q];
        ob[idx] = n * __builtin_amdgcn_rcpf(l);
    }
}

extern "C" void kernel_launch(void* const* d_in, const int* in_sizes, int n_in,
                              void* d_out, int out_size, void* d_ws, size_t ws_size,
                              hipStream_t stream) {
    const float* y  = (const float*)d_in[0];
    const float* Wq = (const float*)d_in[1];
    const float* Wk = (const float*)d_in[2];
    const float* Wv = (const float*)d_in[3];
    float* outp = (float*)d_out;

    const int rows = in_sizes[0] / NINP;       // B*T = 16384
    const int rbn = rows / 64;                 // 256 row-blocks

    ushort* WT = (ushort*)d_ws;                // 3*16384 bf16 = 96 KB (frag-native)
    ushort* Qh = WT + 3 * 16384;               // rows*64 bf16 = 2 MB
    ushort* Kp = Qh + (size_t)rows * DD;       // packed K
    ushort* Vp = Kp + (size_t)rows * DD;       // packed V
    float* part_n = (float*)(Vp + (size_t)rows * DD);   // 256*2*4096 f32 = 8 MB
    float* part_l = part_n + (size_t)256 * 2 * 4096;    // 256*2*64 f32 = 128 KB

    prep_wt<<<3, 256, 0, stream>>>(Wq, Wk, Wv, WT);
    qkv_kernel<<<3 * rbn, 256, 0, stream>>>(y, WT, Qh, Kp, Vp, rbn);
    attn_kernel<<<rbn, 512, 0, stream>>>(Qh, Kp, Vp, part_n, part_l);
    norm_kernel<<<rbn, 256, 0, stream>>>(part_n, part_l, outp);
}

// Round 13
// 101.688 us; speedup vs baseline: 1.0566x; 1.0566x over previous
//
#include <hip/hip_runtime.h>
#include <hip/hip_bf16.h>

#define TLEN 4096
#define NINP 256
#define DD   64

// 1/sqrt(64) * log2(e): folded into WqT so softmax = exp2(s)
#define QSCALE 0.18033688011112042f

typedef __attribute__((ext_vector_type(8))) short bf16x8;
typedef __attribute__((ext_vector_type(4))) short bf16x4;
typedef __attribute__((ext_vector_type(4))) float f32x4;

union U8 { bf16x8 v; uint u[4]; };
union U4 { bf16x4 v; uint u[2]; };

// fp32 -> bf16 RNE (manual; v_cvt_pk_bf16_f32 is NOT RNE -> used only where
// bias is cancelled: P-weights, numerator AND denominator)
__device__ inline ushort bfu(float x) {
    union { float f; uint u; } a; a.f = x;
    uint r = a.u + 0x7fffu + ((a.u >> 16) & 1u);
    return (ushort)(r >> 16);
}
__device__ inline uint pk2(float lo, float hi) {
    return (uint)bfu(lo) | ((uint)bfu(hi) << 16);
}
// hardware packed cvt (non-RNE): P-only (scale-invariance cancels bias)
__device__ inline uint cvtpk(float lo, float hi) {
    uint r;
    asm("v_cvt_pk_bf16_f32 %0, %1, %2" : "=v"(r) : "v"(lo), "v"(hi));
    return r;
}

__device__ inline bf16x8 ld16(const ushort* p) {  // 16B-aligned global/LDS
    return *(const bf16x8*)p;
}

// ---------------------------------------------------------------------------
// prep: WTf[m] in FRAG-NATIVE layout: unit u=(s*4+nt), slot = u*64+lane,
// 16B at slot*8 = W^T[d=nt*16+(lane&15)][k=s*32+(lane>>4)*8 .. +7], Wq scaled.
// ---------------------------------------------------------------------------
__global__ __launch_bounds__(256) void prep_wt(
    const float* __restrict__ Wq, const float* __restrict__ Wk,
    const float* __restrict__ Wv, ushort* __restrict__ WTf)
{
    __shared__ ushort lt[256 * 66];   // [k][d] padded
    const int t = threadIdx.x;
    const int m = blockIdx.x;
    const float* W = (m == 0) ? Wq : ((m == 1) ? Wk : Wv);
    const float scale = (m == 0) ? QSCALE : 1.0f;

    #pragma unroll
    for (int j = 0; j < 16; ++j) {
        int i4 = t + 256 * j;                 // float4 index
        float4 v = *(const float4*)&W[i4 * 4];
        int k = i4 >> 4, d = (i4 * 4) & 63;
        *(uint*)&lt[k * 66 + d]     = pk2(v.x * scale, v.y * scale);
        *(uint*)&lt[k * 66 + d + 2] = pk2(v.z * scale, v.w * scale);
    }
    __syncthreads();
    #pragma unroll
    for (int j = 0; j < 8; ++j) {
        int slot = t + 256 * j;               // 2048 slots x 8 ushort
        int u = slot >> 6, ln = slot & 63;
        int s = u >> 2, nt = u & 3;
        int d = nt * 16 + (ln & 15);
        int k0 = s * 32 + (ln >> 4) * 8;
        uint a0 = (uint)lt[(k0 + 0) * 66 + d] | ((uint)lt[(k0 + 1) * 66 + d] << 16);
        uint a1 = (uint)lt[(k0 + 2) * 66 + d] | ((uint)lt[(k0 + 3) * 66 + d] << 16);
        uint a2 = (uint)lt[(k0 + 4) * 66 + d] | ((uint)lt[(k0 + 5) * 66 + d] << 16);
        uint a3 = (uint)lt[(k0 + 6) * 66 + d] | ((uint)lt[(k0 + 7) * 66 + d] << 16);
        ushort* gd = WTf + m * 16384 + slot * 8;
        ((uint2*)gd)[0] = uint2{a0, a1};
        ((uint2*)gd)[1] = uint2{a2, a3};
    }
}

// ---------------------------------------------------------------------------
// QKV (R13): FUSED m — one 768-thread block (12 waves) per 64-row chunk.
// Wave w: m = w>>2 (Q/K/V), row-group g = w&3. The 3 m-waves of a row-group
// issue the SAME y addresses on the same CU -> 2 of 3 hit L1/L2: HBM y
// traffic 50MB -> 17MB (R3's m-split grid read y 3x). Per-thread work is
// unchanged; occupancy unchanged (12 waves = 3/SIMD). Each m repacks into
// its own tb buffer (26KB LDS), one barrier, then per-m stores via t&255.
// mb=0: Q row-major. mb=1/2: K/V packed frag-native (R8).
// ---------------------------------------------------------------------------
__global__ __launch_bounds__(768) void qkv_kernel(
    const float* __restrict__ y, const ushort* __restrict__ WTf,
    ushort* __restrict__ Qh, ushort* __restrict__ Kp, ushort* __restrict__ Vp)
{
    __shared__ ushort tb[3][64 * 68];  // 26,112 B (one repack buffer per m)

    const int t = threadIdx.x;
    const int w = t >> 6, lane = t & 63;
    const int quad = lane >> 4, l15 = lane & 15;
    const int mb = w >> 2;             // 0=Q 1=K 2=V
    const int g  = w & 3;              // row-group
    const int rb = blockIdx.x;         // rowblock == (batch*64 + chunk64)
    const int rowbase = rb * 64;
    const int myrow = rowbase + g * 16 + l15;

    // ---- A-fragments (same addresses across the 3 m-waves of group g) ----
    bf16x8 afrag[8];
    const float* yrow = y + (size_t)myrow * NINP;
    #pragma unroll
    for (int s = 0; s < 8; ++s) {
        float4 lo = *(const float4*)&yrow[s * 32 + quad * 8];
        float4 hi = *(const float4*)&yrow[s * 32 + quad * 8 + 4];
        U8 u;
        u.u[0] = pk2(lo.x, lo.y);
        u.u[1] = pk2(lo.z, lo.w);
        u.u[2] = pk2(hi.x, hi.y);
        u.u[3] = pk2(hi.z, hi.w);
        afrag[s] = u.v;
    }

    f32x4 acc[4];
    #pragma unroll
    for (int nt = 0; nt < 4; ++nt) acc[nt] = f32x4{0.f, 0.f, 0.f, 0.f};

    const ushort* Wm = WTf + mb * 16384 + lane * 8;
    #pragma unroll
    for (int s = 0; s < 8; ++s)
        #pragma unroll
        for (int nt = 0; nt < 4; ++nt) {
            bf16x8 bfrag = ld16(Wm + (s * 4 + nt) * 512);
            acc[nt] = __builtin_amdgcn_mfma_f32_16x16x32_bf16(
                afrag[s], bfrag, acc[nt], 0, 0, 0);
        }

    // ---- repack into per-m LDS buffer ----
    if (mb < 2) {
        // Q/K: tb[mb][row][d]
        #pragma unroll
        for (int nt = 0; nt < 4; ++nt)
            #pragma unroll
            for (int r = 0; r < 4; ++r)
                tb[mb][(g * 16 + quad * 4 + r) * 68 + nt * 16 + l15] = bfu(acc[nt][r]);
    } else {
        // V: tb[2][d][tt] (pk2 pairs along tt)
        #pragma unroll
        for (int nt = 0; nt < 4; ++nt) {
            int d = nt * 16 + l15;
            #pragma unroll
            for (int r = 0; r < 4; r += 2) {
                int tt = g * 16 + quad * 4 + r;
                *(uint*)&tb[2][d * 68 + tt] = pk2(acc[nt][r], acc[nt][r + 1]);
            }
        }
    }
    __syncthreads();

    // ---- stores: 256 threads per m (tl = t & 255) ----
    const int tl = t & 255;
    if (mb == 0) {
        // Q row-major
        int row = tl >> 2, seg = tl & 3;
        ushort* gd = Qh + (size_t)(rowbase + row) * DD + seg * 16;
        const ushort* sp = &tb[0][row * 68 + seg * 16];
        #pragma unroll
        for (int j = 0; j < 4; ++j) ((uint2*)gd)[j] = ((const uint2*)sp)[j];
    } else if (mb == 1) {
        // K packed: unit idx=(kt*2+s)*64+lane holds 16B of
        // K[row=kt*16+l15][d=s*32+quad*8..+7]
        #pragma unroll
        for (int j = 0; j < 2; ++j) {
            int idx = tl + 256 * j;                // 16B-unit 0..511
            int instr = idx >> 6, ln = idx & 63;
            int kt = instr >> 1, s = instr & 1;
            int q2 = ln >> 4, l15b = ln & 15;
            int row = kt * 16 + l15b, dcol = s * 32 + q2 * 8;
            const ushort* sp = &tb[1][row * 68 + dcol];
            ushort* gd = Kp + (size_t)rb * 4096 + idx * 8;
            ((uint2*)gd)[0] = ((const uint2*)sp)[0];
            ((uint2*)gd)[1] = ((const uint2*)sp)[1];
        }
    } else {
        // V packed: unit idx=(nt*2+m)*64+lane holds two 8B halves
        // V^T[d=nt*16+l15][k=32m+16e+quad*4..+3], e=0,1
        #pragma unroll
        for (int j = 0; j < 2; ++j) {
            int idx = tl + 256 * j;                // 16B-unit 0..511
            int instr = idx >> 6, ln = idx & 63;
            int nt = instr >> 1, m = instr & 1;
            int q2 = ln >> 4, l15b = ln & 15;
            int d = nt * 16 + l15b;
            int k0 = 32 * m + q2 * 4;
            ushort* gd = Vp + (size_t)rb * 4096 + idx * 8;
            ((uint2*)gd)[0] = *(const uint2*)&tb[2][d * 68 + k0];
            ((uint2*)gd)[1] = *(const uint2*)&tb[2][d * 68 + k0 + 16];
        }
    }
}

// ===========================================================================
// Attention helpers: 32-key chunks, packed layout (reverted to R11 exactly —
// best verified config, 100.3us; R12's 64-q + partials combine regressed).
// ===========================================================================
__device__ inline void load_k32(bf16x8 (&kf)[2][2], const ushort* __restrict__ Kw,
                                int ci)
{
    const ushort* base = Kw + (size_t)ci * 2048;
    #pragma unroll
    for (int kt = 0; kt < 2; ++kt)
        #pragma unroll
        for (int s = 0; s < 2; ++s)
            kf[kt][s] = ld16(base + (kt * 2 + s) * 512);
}

__device__ inline void load_v32(U4 (&vt)[4][2], const ushort* __restrict__ Vw,
                                int ci)
{
    const ushort* base = Vw + (size_t)(ci >> 1) * 4096 + (ci & 1) * 512;
    #pragma unroll
    for (int nt = 0; nt < 4; ++nt) {
        U8 uu; uu.v = ld16(base + nt * 1024);
        vt[nt][0].u[0] = uu.u[0]; vt[nt][0].u[1] = uu.u[1];
        vt[nt][1].u[0] = uu.u[2]; vt[nt][1].u[1] = uu.u[3];
    }
}

// one 32-key chunk: compute with kf, prefetch chunk `pf` into kfn (own buffer)
__device__ inline void chunk32(
    const bf16x8 (&kf)[2][2], bf16x8 (&kfn)[2][2],
    const ushort* __restrict__ Kw, const ushort* __restrict__ Vw,
    const bf16x8 (&qf)[2][2], f32x4 (&oT)[2][4], float (&l_acc)[2],
    int ci, int pf, int chi, int qb, int quad, int l15)
{
    const int c0 = ci * 32;
    U4 vt[4][2];
    load_v32(vt, Vw, ci);

    // S^T = K·Q^T
    f32x4 st[2][2];
    #pragma unroll
    for (int qt = 0; qt < 2; ++qt)
        #pragma unroll
        for (int kt = 0; kt < 2; ++kt)
            st[qt][kt] = f32x4{0.f, 0.f, 0.f, 0.f};
    __builtin_amdgcn_s_setprio(1);
    #pragma unroll
    for (int s = 0; s < 2; ++s)
        #pragma unroll
        for (int qt = 0; qt < 2; ++qt)
            #pragma unroll
            for (int kt = 0; kt < 2; ++kt)
                st[qt][kt] = __builtin_amdgcn_mfma_f32_16x16x32_bf16(
                    kf[kt][s], qf[qt][s], st[qt][kt], 0, 0, 0);
    __builtin_amdgcn_s_setprio(0);

    // prefetch 2-ahead into own buffer (reads of kf already consumed)
    if (pf < chi) load_k32(kfn, Kw, pf);

    // softmax weights -> bf16 P^T frags (cvt_pk; bias cancels in O)
    U4 pa[2][2];
    if (c0 + 31 <= qb) {            // wave-uniform: fully unmasked chunk
        #pragma unroll
        for (int qt = 0; qt < 2; ++qt)
            #pragma unroll
            for (int kt = 0; kt < 2; ++kt) {
                float p0 = exp2f(st[qt][kt][0]);
                float p1 = exp2f(st[qt][kt][1]);
                float p2 = exp2f(st[qt][kt][2]);
                float p3 = exp2f(st[qt][kt][3]);
                l_acc[qt] += (p0 + p1) + (p2 + p3);
                pa[qt][kt].u[0] = cvtpk(p0, p1);
                pa[qt][kt].u[1] = cvtpk(p2, p3);
            }
    } else {                        // diagonal chunk: causal mask
        #pragma unroll
        for (int qt = 0; qt < 2; ++qt) {
            const int q = qb + qt * 16 + l15;
            #pragma unroll
            for (int kt = 0; kt < 2; ++kt) {
                const int kb0 = c0 + kt * 16 + quad * 4;
                float p[4];
                #pragma unroll
                for (int r = 0; r < 4; ++r) {
                    float e = exp2f(st[qt][kt][r]);
                    p[r] = (kb0 + r <= q) ? e : 0.f;
                    l_acc[qt] += p[r];
                }
                pa[qt][kt].u[0] = cvtpk(p[0], p[1]);
                pa[qt][kt].u[1] = cvtpk(p[2], p[3]);
            }
        }
    }

    // O^T += V^T·P^T (16x16x16, K=16: B-layout == S^T lane layout)
    __builtin_amdgcn_s_setprio(1);
    #pragma unroll
    for (int qt = 0; qt < 2; ++qt)
        #pragma unroll
        for (int nt = 0; nt < 4; ++nt)
            #pragma unroll
            for (int kt = 0; kt < 2; ++kt)
                oT[qt][nt] = __builtin_amdgcn_mfma_f32_16x16x16bf16_1k(
                    vt[nt][kt].v, pa[qt][kt].v, oT[qt][nt], 0, 0, 0);
    __builtin_amdgcn_s_setprio(0);
}

// ---------------------------------------------------------------------------
// Attention (R11 config): 256 blocks x 768 threads (12 waves, 1 block/CU,
// 3 waves/SIMD flat). Block = complete snake pair (129 chunk-32s uniform),
// 12-way key-seg split. K prefetch 2-deep ping-pong. P via cvt_pk (bias
// cancels). XCD-batch clustering: batch=(id&7)>>1 -> K+V L2-resident.
// ---------------------------------------------------------------------------
__global__ __launch_bounds__(768, 3) void attn_kernel(
    const ushort* __restrict__ Qh, const ushort* __restrict__ Kp,
    const ushort* __restrict__ Vp, float* __restrict__ out)
{
    __shared__ float Ob[12][32 * 68];   // per-wave partial O [q][d] padded
    __shared__ float lb[12][32];        // per-wave partial l

    const int t = threadIdx.x;
    const int w = t >> 6, lane = t & 63;
    const int quad = lane >> 4, l15 = lane & 15;

    // XCD-clustered decode (grid = 256 = 4 batches x 64 pairs)
    const int x  = blockIdx.x & 7;
    const int b  = x >> 1;
    const int pr = (((int)blockIdx.x >> 3) << 1) | (x & 1);   // 0..63

    const ushort* Qb = Qh + (size_t)b * TLEN * DD;
    const ushort* Kw = Kp + (size_t)b * 64 * 4096 + lane * 8;
    const ushort* Vw = Vp + (size_t)b * 64 * 4096 + lane * 8;
    float* outb = out + (size_t)b * TLEN * DD;

    for (int half = 0; half < 2; ++half) {
        const int tile = half ? (127 - pr) : pr;
        const int seg  = half ? (11 - w) : w;
        const int qb   = tile * 32;
        const int nc   = tile + 1;                    // 32-key chunks
        const int cps  = (nc + 11) / 12;
        const int clo  = seg * cps;
        const int chi  = (nc < clo + cps) ? nc : (clo + cps);

        f32x4 oT[2][4];                  // O^T: d=nt*16+quad*4+r, q=qb+qt*16+l15
        #pragma unroll
        for (int qt = 0; qt < 2; ++qt)
            #pragma unroll
            for (int nt = 0; nt < 4; ++nt)
                oT[qt][nt] = f32x4{0.f, 0.f, 0.f, 0.f};
        float l_acc[2] = {0.f, 0.f};

        if (clo < chi) {
            // Q B-frags (fixed per tile)
            bf16x8 qf[2][2];
            #pragma unroll
            for (int qt = 0; qt < 2; ++qt)
                #pragma unroll
                for (int s = 0; s < 2; ++s)
                    qf[qt][s] = ld16(Qb + (size_t)(qb + qt * 16 + l15) * DD + s * 32 + quad * 8);

            // K ping-pong prologue: A <- clo, B <- clo+1
            bf16x8 kfA[2][2], kfB[2][2];
            load_k32(kfA, Kw, clo);
            if (clo + 1 < chi) load_k32(kfB, Kw, clo + 1);

            for (int ci = clo; ci < chi; ci += 2) {
                chunk32(kfA, kfA, Kw, Vw, qf, oT, l_acc,
                        ci, ci + 2, chi, qb, quad, l15);
                if (ci + 1 < chi)
                    chunk32(kfB, kfB, Kw, Vw, qf, oT, l_acc,
                            ci + 1, ci + 3, chi, qb, quad, l15);
            }

            // reduce l across quads (keys live in quads)
            #pragma unroll
            for (int qt = 0; qt < 2; ++qt) {
                l_acc[qt] += __shfl_xor(l_acc[qt], 16, 64);
                l_acc[qt] += __shfl_xor(l_acc[qt], 32, 64);
            }
        }

        // publish partials (zeros if empty task)
        #pragma unroll
        for (int qt = 0; qt < 2; ++qt) {
            #pragma unroll
            for (int nt = 0; nt < 4; ++nt)
                #pragma unroll
                for (int r = 0; r < 4; ++r)
                    Ob[w][(qt * 16 + l15) * 68 + nt * 16 + quad * 4 + r] = oT[qt][nt][r];
            if (quad == 0) lb[w][qt * 16 + l15] = l_acc[qt];
        }
        __syncthreads();

        // in-block combine + store (complete: all 12 segs of this tile here)
        #pragma unroll
        for (int e = 0; e < 3; ++e) {
            int idx = t + 768 * e;
            if (idx < 2048) {
                int q = idx >> 6, d = idx & 63;
                float s = 0.f, ls = 0.f;
                #pragma unroll
                for (int ww = 0; ww < 12; ++ww) {
                    s += Ob[ww][q * 68 + d];
                    ls += lb[ww][q];
                }
                outb[(size_t)(qb + q) * DD + d] = s * __builtin_amdgcn_rcpf(ls);
            }
        }
        __syncthreads();
    }
}

extern "C" void kernel_launch(void* const* d_in, const int* in_sizes, int n_in,
                              void* d_out, int out_size, void* d_ws, size_t ws_size,
                              hipStream_t stream) {
    const float* y  = (const float*)d_in[0];
    const float* Wq = (const float*)d_in[1];
    const float* Wk = (const float*)d_in[2];
    const float* Wv = (const float*)d_in[3];
    float* outp = (float*)d_out;

    const int rows = in_sizes[0] / NINP;       // B*T = 16384
    const int nb = rows / TLEN;                // batches = 4
    const int rbn = rows / 64;                 // 256 row-blocks

    ushort* WT = (ushort*)d_ws;                // 3*16384 bf16 = 96 KB (frag-native)
    ushort* Qh = WT + 3 * 16384;               // rows*64 bf16 = 2 MB
    ushort* Kp = Qh + (size_t)rows * DD;       // packed K
    ushort* Vp = Kp + (size_t)rows * DD;       // packed V

    prep_wt<<<3, 256, 0, stream>>>(Wq, Wk, Wv, WT);
    qkv_kernel<<<rbn, 768, 0, stream>>>(y, WT, Qh, Kp, Vp);
    attn_kernel<<<nb * 64, 768, 0, stream>>>(Qh, Kp, Vp, outp);
}